// Round 1
// baseline (389.078 us; speedup 1.0000x reference)
//
#include <hip/hip_runtime.h>
#include <hip/hip_bf16.h>
#include <cstdint>

// MFVI second-order CRF message passing, B=32 S=1024 T=256 WINDOW=2 ITER=3.
// msg = Shift(P) @ Wc  as one GEMM: M=32768, N=256, K=1024 (4 shift regions).
//
// ws layout: P bf16 [32768][256] @ 0 (16MB) | Q f32 [32768][256] @ 16MB (32MB)
//            WcT bf16 [256][1024] @ 48MB (512KB)

typedef __attribute__((ext_vector_type(4))) float f32x4;
typedef __attribute__((ext_vector_type(8))) short bf16x8;

// Build WcT[n][k]: k<256: T1[k][n] ; k<512: T2[k-256][n] ; k<768: T1[n][k-512] ; else T2[n][k-768]
__global__ void prep_wct(const float* __restrict__ trans, __hip_bfloat16* __restrict__ wct) {
    int n = blockIdx.x;     // 0..255
    int k = threadIdx.x;    // 0..1023
    int r = k >> 8;
    int kk = k & 255;
    float v;
    if (r == 0)      v = trans[kk * 256 + n];
    else if (r == 1) v = trans[65536 + kk * 256 + n];
    else if (r == 2) v = trans[n * 256 + kk];
    else             v = trans[65536 + n * 256 + kk];
    wct[n * 1024 + k] = __float2bfloat16(v);
}

// One wave per row of [32768][256]. p = softmax(src*mask). Masked rows (all
// zero) -> uniform 1/256, matching the reference's softmax-of-zeros.
__global__ __launch_bounds__(256) void softmax_rows(
    const float* __restrict__ src, const int* __restrict__ lengths,
    __hip_bfloat16* __restrict__ P)
{
    int row  = blockIdx.x * 4 + (threadIdx.x >> 6);
    int lane = threadIdx.x & 63;
    int b = row >> 10, s = row & 1023;
    float mval = (s < lengths[b]) ? 1.f : 0.f;
    float4 x = *((const float4*)(src + row * 256 + lane * 4));
    x.x *= mval; x.y *= mval; x.z *= mval; x.w *= mval;
    float mx = fmaxf(fmaxf(x.x, x.y), fmaxf(x.z, x.w));
    #pragma unroll
    for (int o = 32; o; o >>= 1) mx = fmaxf(mx, __shfl_xor(mx, o));
    float e0 = __expf(x.x - mx), e1 = __expf(x.y - mx);
    float e2 = __expf(x.z - mx), e3 = __expf(x.w - mx);
    float sum = e0 + e1 + e2 + e3;
    #pragma unroll
    for (int o = 32; o; o >>= 1) sum += __shfl_xor(sum, o);
    float inv = 1.0f / sum;
    union { ushort4 u; __hip_bfloat16 h[4]; } o4;
    o4.h[0] = __float2bfloat16(e0 * inv);
    o4.h[1] = __float2bfloat16(e1 * inv);
    o4.h[2] = __float2bfloat16(e2 * inv);
    o4.h[3] = __float2bfloat16(e3 * inv);
    *((ushort4*)(P + row * 256 + lane * 4)) = o4.u;
}

// 128x128 tile GEMM over K=1024, A = shift-window reads of P (zero-filled at
// sequence edges), B = WcT. Fused epilogue: + start/end transitions, + unary,
// * mask, store fp32.
__global__ __launch_bounds__(256) void gemm_msg(
    const __hip_bfloat16* __restrict__ P,    // [32768][256]
    const __hip_bfloat16* __restrict__ WcT,  // [256][1024]
    const float* __restrict__ unary,         // [32768][256]
    const int* __restrict__ lengths,         // [32]
    const float* __restrict__ startT,        // [2][256]
    const float* __restrict__ endT,          // [2][256]
    float* __restrict__ dst)                 // [32768][256]
{
    __shared__ __hip_bfloat16 As[128][72];   // 64 k + 8 pad
    __shared__ __hip_bfloat16 Bs[128][72];

    int mblk = blockIdx.x;                   // 0..255
    int nblk = blockIdx.y;                   // 0..1
    int b  = mblk >> 3;
    int s0 = (mblk & 7) << 7;                // seq offset within batch
    int n0 = nblk << 7;
    int tid  = threadIdx.x;
    int lane = tid & 63, wid = tid >> 6;
    int wm = (wid >> 1) * 64, wn = (wid & 1) * 64;

    f32x4 acc[4][4] = {};

    const __hip_bfloat16* Pb = P + ((long)(b << 10)) * 256;

    for (int ks = 0; ks < 16; ++ks) {
        int k0 = ks << 6;
        int region = ks >> 2;                // 0..3 -> shift -1,-2,+1,+2
        int delta = (region == 0) ? -1 : (region == 1) ? -2 : (region == 2) ? 1 : 2;
        int a0 = (ks & 3) << 6;              // column window within P row

        // stage A: 128 rows x 64 cols bf16 = 1024 chunks of 16B, 4/thread
        #pragma unroll
        for (int t = 0; t < 4; ++t) {
            int c = tid + t * 256;
            int r = c >> 3;
            int col = (c & 7) << 3;          // bf16 elements
            int ss = s0 + r + delta;
            uint4 val = {0u, 0u, 0u, 0u};
            if ((unsigned)ss < 1024u)
                val = *((const uint4*)(Pb + ss * 256 + a0 + col));
            *((uint4*)(&As[r][col])) = val;
        }
        // stage B
        #pragma unroll
        for (int t = 0; t < 4; ++t) {
            int c = tid + t * 256;
            int r = c >> 3;
            int col = (c & 7) << 3;
            uint4 val = *((const uint4*)(WcT + (n0 + r) * 1024 + k0 + col));
            *((uint4*)(&Bs[r][col])) = val;
        }
        __syncthreads();

        #pragma unroll
        for (int kk = 0; kk < 2; ++kk) {
            int koff = kk * 32 + ((lane >> 4) << 3);
            bf16x8 afrag[4], bfrag[4];
            #pragma unroll
            for (int i = 0; i < 4; ++i)
                afrag[i] = *((const bf16x8*)(&As[wm + i * 16 + (lane & 15)][koff]));
            #pragma unroll
            for (int i = 0; i < 4; ++i)
                bfrag[i] = *((const bf16x8*)(&Bs[wn + i * 16 + (lane & 15)][koff]));
            #pragma unroll
            for (int i = 0; i < 4; ++i)
                #pragma unroll
                for (int j = 0; j < 4; ++j)
                    acc[i][j] = __builtin_amdgcn_mfma_f32_16x16x32_bf16(
                        afrag[i], bfrag[j], acc[i][j], 0, 0, 0);
        }
        __syncthreads();
    }

    // epilogue: C/D layout col=lane&15, row=(lane>>4)*4+reg
    int len  = lengths[b];
    int quad = lane >> 4;
    int cn   = lane & 15;
    #pragma unroll
    for (int i = 0; i < 4; ++i) {
        int srow = s0 + wm + i * 16 + quad * 4;
        #pragma unroll
        for (int j = 0; j < 4; ++j) {
            int n = n0 + wn + j * 16 + cn;
            #pragma unroll
            for (int r = 0; r < 4; ++r) {
                int s = srow + r;
                float v = acc[i][j][r];
                if (s == 0)       v += startT[n];
                if (s == 1)       v += startT[256 + n];
                if (s == len - 1) v += endT[n];
                if (s == len - 2) v += endT[256 + n];
                long idx = ((long)((b << 10) + s)) * 256 + n;
                dst[idx] = (s < len) ? (unary[idx] + v) : 0.f;
            }
        }
    }
}

extern "C" void kernel_launch(void* const* d_in, const int* in_sizes, int n_in,
                              void* d_out, int out_size, void* d_ws, size_t ws_size,
                              hipStream_t stream) {
    const float* unary  = (const float*)d_in[1];
    const float* trans  = (const float*)d_in[3];
    const float* startT = (const float*)d_in[4];
    const float* endT   = (const float*)d_in[5];
    const int*   lens   = (const int*)d_in[6];

    char* ws = (char*)d_ws;
    __hip_bfloat16* P   = (__hip_bfloat16*)ws;                       // 16 MB
    float*          Q   = (float*)(ws + (size_t)(16u << 20));        // 32 MB
    __hip_bfloat16* WcT = (__hip_bfloat16*)(ws + (size_t)(48u << 20)); // 512 KB

    prep_wct<<<dim3(256), dim3(1024), 0, stream>>>(trans, WcT);

    // iteration 1 (q0 = unary*mask, mask applied inside softmax)
    softmax_rows<<<dim3(8192), dim3(256), 0, stream>>>(unary, lens, P);
    gemm_msg<<<dim3(256, 2), dim3(256), 0, stream>>>(P, WcT, unary, lens, startT, endT, Q);
    // iteration 2
    softmax_rows<<<dim3(8192), dim3(256), 0, stream>>>(Q, lens, P);
    gemm_msg<<<dim3(256, 2), dim3(256), 0, stream>>>(P, WcT, unary, lens, startT, endT, Q);
    // iteration 3 -> d_out
    softmax_rows<<<dim3(8192), dim3(256), 0, stream>>>(Q, lens, P);
    gemm_msg<<<dim3(256, 2), dim3(256), 0, stream>>>(P, WcT, unary, lens, startT, endT, (float*)d_out);
}

// Round 2
// 303.972 us; speedup vs baseline: 1.2800x; 1.2800x over previous
//
#include <hip/hip_runtime.h>
#include <hip/hip_bf16.h>
#include <cstdint>

// MFVI second-order CRF, B=32 S=1024 T=256 W=2 ITER=3.
// msg = Shift(P) @ Wc as one GEMM: M=32768, N=256, K=1024 (4 shift regions).
// Round 2: global_load_lds async staging (XOR-swizzled, guard-padded P),
// softmax fused into GEMM epilogue (tile 64x256 = full rows).
//
// ws: Pa bf16 [32][1028][256] @0 | Pb same @32MB | WcT bf16 [256][1024] @64MB

typedef __attribute__((ext_vector_type(4))) float f32x4;
typedef __attribute__((ext_vector_type(8))) short bf16x8;

__device__ __forceinline__ void load_lds16(const void* g, void* l) {
    __builtin_amdgcn_global_load_lds(
        (const __attribute__((address_space(1))) void*)g,
        (__attribute__((address_space(3))) void*)l, 16, 0, 0);
}

// WcT[n][k]: k<256: T1[k][n]; <512: T2[..][n]; <768: T1[n][..]; else T2[n][..]
// Also zeroes the 4 guard rows per batch of both P buffers (ws is re-poisoned
// to 0xAA before every call, so this must run every call).
__global__ void prep_wct(const float* __restrict__ trans,
                         __hip_bfloat16* __restrict__ wct,
                         __hip_bfloat16* __restrict__ Pa,
                         __hip_bfloat16* __restrict__ Pb) {
    int n = blockIdx.x;     // 0..255
    int k = threadIdx.x;    // 0..1023
    int r = k >> 8, kk = k & 255;
    float v;
    if (r == 0)      v = trans[kk * 256 + n];
    else if (r == 1) v = trans[65536 + kk * 256 + n];
    else if (r == 2) v = trans[n * 256 + kk];
    else             v = trans[65536 + n * 256 + kk];
    wct[n * 1024 + k] = __float2bfloat16(v);
    if (threadIdx.x < 256) {
        int g = blockIdx.x * 256 + threadIdx.x;       // 0..65535
        __hip_bfloat16* P = (g & 32768) ? Pb : Pa;
        int rem = g & 32767;
        int b = rem >> 10, wr = (rem >> 8) & 3, col = rem & 255;
        int row = b * 1028 + ((wr < 2) ? wr : 1024 + wr);  // 0,1,1026,1027
        P[row * 256 + col] = __float2bfloat16(0.f);
    }
}

// Initial softmax: P = softmax(unary * mask) row-wise, into padded layout.
__global__ __launch_bounds__(256) void softmax0(
    const float* __restrict__ src, const int* __restrict__ lengths,
    __hip_bfloat16* __restrict__ P)
{
    int row  = blockIdx.x * 4 + (threadIdx.x >> 6);
    int lane = threadIdx.x & 63;
    int b = row >> 10, s = row & 1023;
    float mval = (s < lengths[b]) ? 1.f : 0.f;
    float4 x = *((const float4*)(src + row * 256 + lane * 4));
    x.x *= mval; x.y *= mval; x.z *= mval; x.w *= mval;
    float mx = fmaxf(fmaxf(x.x, x.y), fmaxf(x.z, x.w));
    #pragma unroll
    for (int o = 32; o; o >>= 1) mx = fmaxf(mx, __shfl_xor(mx, o));
    float e0 = __expf(x.x - mx), e1 = __expf(x.y - mx);
    float e2 = __expf(x.z - mx), e3 = __expf(x.w - mx);
    float sum = e0 + e1 + e2 + e3;
    #pragma unroll
    for (int o = 32; o; o >>= 1) sum += __shfl_xor(sum, o);
    float inv = 1.0f / sum;
    union { ushort4 u; __hip_bfloat16 h[4]; } o4;
    o4.h[0] = __float2bfloat16(e0 * inv);
    o4.h[1] = __float2bfloat16(e1 * inv);
    o4.h[2] = __float2bfloat16(e2 * inv);
    o4.h[3] = __float2bfloat16(e3 * inv);
    *((ushort4*)(P + (b * 1028 + 2 + s) * 256 + lane * 4)) = o4.u;
}

// Fused iteration: msg GEMM (64x256 tile, K=1024) + boundary + unary, then
// either row-softmax -> Pout (bf16, padded) or masked fp32 -> qout (final).
__global__ __launch_bounds__(256) void mfvi_iter(
    const __hip_bfloat16* __restrict__ Pin,   // [32][1028][256] padded
    const __hip_bfloat16* __restrict__ WcT,   // [256][1024]
    const float* __restrict__ unary,          // [32768][256]
    const int* __restrict__ lengths,
    const float* __restrict__ startT,         // [2][256]
    const float* __restrict__ endT,           // [2][256]
    __hip_bfloat16* __restrict__ Pout,
    float* __restrict__ qout,
    int final_iter)
{
    // Unpadded LDS (global_load_lds requires lane-contiguous dest); XOR
    // chunk swizzle in the *global* address keeps ds_read_b128 ~conflict-free.
    __shared__ __hip_bfloat16 As[64 * 64];    // 8 KB  (row*128B, 8 chunks)
    __shared__ __hip_bfloat16 Bs[256 * 64];   // 32 KB
    __shared__ float redA[256];               // [wave][row]
    __shared__ float redB[256];

    int mblk = blockIdx.x;                    // 0..511
    int b  = mblk >> 4;
    int s0 = (mblk & 15) << 6;
    int tid = threadIdx.x;
    int lane = tid & 63, wid = tid >> 6;
    int wn = wid << 6;
    int cn = lane & 15, quad = lane >> 4;

    const __hip_bfloat16* Pbase = Pin + (size_t)b * 1028 * 256;
    int sr = tid >> 3;        // staging row within a 32-row call
    int sc = tid & 7;         // staging chunk 0..7

    f32x4 acc[4][4] = {};

    for (int ks = 0; ks < 16; ++ks) {
        int region = ks >> 2;
        int delta = (region == 0) ? -1 : (region == 1) ? -2 : (region == 2) ? 1 : 2;
        int a0 = (ks & 3) << 6;               // P column chunk
        int k0 = ks << 6;                     // WcT k offset

        // A: 64 rows x 128B, 2 calls; guard rows supply zeros (no branch)
        #pragma unroll
        for (int c = 0; c < 2; ++c) {
            int r = c * 32 + sr;
            int grow = 2 + s0 + r + delta;
            const __hip_bfloat16* g = Pbase + grow * 256 + a0 + ((sc ^ (r & 7)) << 3);
            load_lds16(g, (char*)As + c * 4096 + tid * 16);
        }
        // B: 256 rows x 128B, 8 calls
        #pragma unroll
        for (int c = 0; c < 8; ++c) {
            int n = c * 32 + sr;
            const __hip_bfloat16* g = WcT + n * 1024 + k0 + ((sc ^ (n & 7)) << 3);
            load_lds16(g, (char*)Bs + c * 4096 + tid * 16);
        }
        __syncthreads();

        #pragma unroll
        for (int kk = 0; kk < 2; ++kk) {
            int q = (kk << 2) + quad;         // k-chunk index 0..7
            bf16x8 af[4], bfv[4];
            #pragma unroll
            for (int i = 0; i < 4; ++i) {
                int m = (i << 4) + cn;
                af[i] = *(const bf16x8*)((char*)As + m * 128 + ((q ^ (m & 7)) << 4));
            }
            #pragma unroll
            for (int j = 0; j < 4; ++j) {
                int n = wn + (j << 4) + cn;
                bfv[j] = *(const bf16x8*)((char*)Bs + n * 128 + ((q ^ (n & 7)) << 4));
            }
            #pragma unroll
            for (int i = 0; i < 4; ++i)
                #pragma unroll
                for (int j = 0; j < 4; ++j)
                    acc[i][j] = __builtin_amdgcn_mfma_f32_16x16x32_bf16(
                        af[i], bfv[j], acc[i][j], 0, 0, 0);
        }
        __syncthreads();
    }

    // Epilogue. C/D: col=lane&15, row=quad*4+reg.
    int len = lengths[b];
    #pragma unroll
    for (int i = 0; i < 4; ++i) {
        #pragma unroll
        for (int j = 0; j < 4; ++j) {
            int n = wn + (j << 4) + cn;
            #pragma unroll
            for (int r = 0; r < 4; ++r) {
                int s = s0 + (i << 4) + (quad << 2) + r;
                float x = acc[i][j][r];
                if (s == 0)       x += startT[n];
                if (s == 1)       x += startT[256 + n];
                if (s == len - 1) x += endT[n];
                if (s == len - 2) x += endT[256 + n];
                long idx = ((long)((b << 10) + s)) * 256 + n;
                x += unary[idx];
                acc[i][j][r] = (s < len) ? x : 0.f;
            }
        }
    }

    if (final_iter) {
        #pragma unroll
        for (int i = 0; i < 4; ++i)
            #pragma unroll
            for (int j = 0; j < 4; ++j) {
                int n = wn + (j << 4) + cn;
                #pragma unroll
                for (int r = 0; r < 4; ++r) {
                    int s = s0 + (i << 4) + (quad << 2) + r;
                    qout[((long)((b << 10) + s)) * 256 + n] = acc[i][j][r];
                }
            }
        return;
    }

    // Fused row softmax over 256 cols: quad shfl-reduce (16 lanes hold a
    // row's 64 cols of this wave) then 4-wave LDS combine.
    #pragma unroll
    for (int i = 0; i < 4; ++i)
        #pragma unroll
        for (int r = 0; r < 4; ++r) {
            float m4 = fmaxf(fmaxf(acc[i][0][r], acc[i][1][r]),
                             fmaxf(acc[i][2][r], acc[i][3][r]));
            m4 = fmaxf(m4, __shfl_xor(m4, 1));
            m4 = fmaxf(m4, __shfl_xor(m4, 2));
            m4 = fmaxf(m4, __shfl_xor(m4, 4));
            m4 = fmaxf(m4, __shfl_xor(m4, 8));
            if (cn == 0) redA[(wid << 6) + (i << 4) + (quad << 2) + r] = m4;
        }
    __syncthreads();
    float M[4][4];
    #pragma unroll
    for (int i = 0; i < 4; ++i)
        #pragma unroll
        for (int r = 0; r < 4; ++r) {
            int row = (i << 4) + (quad << 2) + r;
            M[i][r] = fmaxf(fmaxf(redA[row], redA[64 + row]),
                            fmaxf(redA[128 + row], redA[192 + row]));
        }
    #pragma unroll
    for (int i = 0; i < 4; ++i)
        #pragma unroll
        for (int r = 0; r < 4; ++r) {
            float s4 = 0.f;
            #pragma unroll
            for (int j = 0; j < 4; ++j) {
                float e = __expf(acc[i][j][r] - M[i][r]);
                acc[i][j][r] = e;
                s4 += e;
            }
            s4 += __shfl_xor(s4, 1);
            s4 += __shfl_xor(s4, 2);
            s4 += __shfl_xor(s4, 4);
            s4 += __shfl_xor(s4, 8);
            if (cn == 0) redB[(wid << 6) + (i << 4) + (quad << 2) + r] = s4;
        }
    __syncthreads();
    #pragma unroll
    for (int i = 0; i < 4; ++i)
        #pragma unroll
        for (int r = 0; r < 4; ++r) {
            int row = (i << 4) + (quad << 2) + r;
            float inv = 1.0f / (redB[row] + redB[64 + row] +
                                redB[128 + row] + redB[192 + row]);
            int s = s0 + row;
            #pragma unroll
            for (int j = 0; j < 4; ++j) {
                int n = wn + (j << 4) + cn;
                Pout[((size_t)b * 1028 + 2 + s) * 256 + n] =
                    __float2bfloat16(acc[i][j][r] * inv);
            }
        }
}

extern "C" void kernel_launch(void* const* d_in, const int* in_sizes, int n_in,
                              void* d_out, int out_size, void* d_ws, size_t ws_size,
                              hipStream_t stream) {
    const float* unary  = (const float*)d_in[1];
    const float* trans  = (const float*)d_in[3];
    const float* startT = (const float*)d_in[4];
    const float* endT   = (const float*)d_in[5];
    const int*   lens   = (const int*)d_in[6];

    char* ws = (char*)d_ws;
    __hip_bfloat16* Pa  = (__hip_bfloat16*)ws;                          // 16.8 MB
    __hip_bfloat16* Pb  = (__hip_bfloat16*)(ws + ((size_t)32 << 20));   // 16.8 MB
    __hip_bfloat16* WcT = (__hip_bfloat16*)(ws + ((size_t)64 << 20));   // 512 KB

    prep_wct<<<dim3(256), dim3(1024), 0, stream>>>(trans, WcT, Pa, Pb);
    softmax0<<<dim3(8192), dim3(256), 0, stream>>>(unary, lens, Pa);
    mfvi_iter<<<dim3(512), dim3(256), 0, stream>>>(Pa, WcT, unary, lens, startT, endT, Pb, nullptr, 0);
    mfvi_iter<<<dim3(512), dim3(256), 0, stream>>>(Pb, WcT, unary, lens, startT, endT, Pa, nullptr, 0);
    mfvi_iter<<<dim3(512), dim3(256), 0, stream>>>(Pa, WcT, unary, lens, startT, endT, nullptr, (float*)d_out, 1);
}